// Round 11
// baseline (99.003 us; speedup 1.0000x reference)
//
#include <hip/hip_runtime.h>
#include <stdint.h>

// ---- problem constants ----
#define NPARTS 16
#define NK1    257            // rows per part (hash values 0..256)
#define ROWS   4112           // 257*16 distinct embedding rows
#define MPAD   4224           // 66*64, padded GEMM M
#define VAE    768
#define ODIM   1024
#define BROWS  65536          // 4096*16 output rows
#define BPART  4096           // output rows per part

typedef __attribute__((ext_vector_type(4))) float f32x4;
typedef __attribute__((ext_vector_type(8))) short s16x8;

static __device__ __forceinline__ unsigned short f2bf(float f) {
  union { float f; unsigned u; } v; v.f = f;
  unsigned x = v.u;
  unsigned r = x + 0x7FFFu + ((x >> 16) & 1u);   // RNE
  return (unsigned short)(r >> 16);
}

static __device__ __forceinline__ void gload_lds16(const void* g, void* l) {
  __builtin_amdgcn_global_load_lds(
      (const __attribute__((address_space(1))) unsigned int*)g,
      (__attribute__((address_space(3))) unsigned int*)l, 16, 0, 0);
}

// ---------------- prep: emb->bf16 cast | W1 transpose-cast | consumer-index build ----
// grid: [0,1024) emb cast; [1024,1792) W1 tiles; [1792,1808) per-part counting sort.
// Sort emits ents[] sorted by table row tr=p*257+h, packed ((tr&63)<<16)|orow,
// and glob64[g] = index of first entry with tr >= 64g (g=0..66). R4-proven logic.
#define EMB_BLOCKS 1024
#define W1_BLOCKS  768
__global__ __launch_bounds__(256) void prep_kernel(
    const float* __restrict__ emb, const float* __restrict__ W1,
    const int* __restrict__ hashes,
    unsigned short* __restrict__ embB, unsigned short* __restrict__ w1t,
    int* __restrict__ ents, int* __restrict__ glob64) {
  __shared__ unsigned short tile[32][33];
  __shared__ int hist[512];
  const int tid = threadIdx.x;
  const int bid = blockIdx.x;
  if (bid < EMB_BLOCKS) {
    const int NQ = MPAD * VAE / 4;   // 811008 quads
    for (int g = bid * 256 + tid; g < NQ; g += EMB_BLOCKS * 256) {
      const int i4 = g * 4;
      ushort4 o;
      if (i4 < ROWS * VAE) {
        const float4 v = *(const float4*)(emb + i4);
        o.x = f2bf(v.x); o.y = f2bf(v.y); o.z = f2bf(v.z); o.w = f2bf(v.w);
      } else {
        o.x = 0; o.y = 0; o.z = 0; o.w = 0;
      }
      *(ushort4*)(embB + i4) = o;
    }
  } else if (bid < EMB_BLOCKS + W1_BLOCKS) {
    const int tb = bid - EMB_BLOCKS;         // 24 k-tiles x 32 n-tiles
    const int nkt = VAE / 32;
    const int tk = (tb % nkt) * 32;
    const int tn = (tb / nkt) * 32;
    const int r  = tid >> 3;
    const int c4 = (tid & 7) * 4;
    const float4 v = *(const float4*)(W1 + (size_t)(tk + r) * ODIM + tn + c4);
    tile[r][c4 + 0] = f2bf(v.x);
    tile[r][c4 + 1] = f2bf(v.y);
    tile[r][c4 + 2] = f2bf(v.z);
    tile[r][c4 + 3] = f2bf(v.w);
    __syncthreads();
    ushort4 o;
    o.x = tile[c4 + 0][r];
    o.y = tile[c4 + 1][r];
    o.z = tile[c4 + 2][r];
    o.w = tile[c4 + 3][r];
    *(ushort4*)(w1t + (size_t)(tn + r) * VAE + tk + c4) = o;
  } else {
    // ---- counting sort of part p's 4096 rows into 257 buckets (R4-proven) ----
    const int p = bid - (EMB_BLOCKS + W1_BLOCKS);
    hist[tid] = 0; hist[tid + 256] = 0;
    __syncthreads();
    int hv[16];
#pragma unroll
    for (int u = 0; u < 16; ++u) {
      const int b = u * 256 + tid;
      hv[u] = hashes[b * NPARTS + p];
      atomicAdd(&hist[hv[u]], 1);
    }
    __syncthreads();
    const int o0 = hist[tid], o1 = hist[tid + 256];
    // inclusive Hillis-Steele scan over 512 (2 slots/thread)
    for (int off = 1; off < 512; off <<= 1) {
      const int v0 = (tid >= off) ? hist[tid - off] : 0;
      const int v1 = hist[tid + 256 - off];
      __syncthreads();
      hist[tid] += v0; hist[tid + 256] += v1;
      __syncthreads();
    }
    const int b0 = hist[tid] - o0;          // exclusive base (h = tid)
    const int b1 = hist[tid + 256] - o1;    // exclusive base (h = tid+256)
    const int tr0 = p * NK1 + tid;
    if ((tr0 & 63) == 0) glob64[tr0 >> 6] = p * BPART + b0;
    if (tid == 0) {
      const int tr1 = p * NK1 + 256;
      if ((tr1 & 63) == 0) glob64[tr1 >> 6] = p * BPART + b1;
      if (p == NPARTS - 1) { glob64[65] = BROWS; glob64[66] = BROWS; }
    }
    __syncthreads();
    hist[tid] = b0; hist[tid + 256] = b1;   // cursors
    __syncthreads();
#pragma unroll
    for (int u = 0; u < 16; ++u) {
      const int b = u * 256 + tid;
      const int pos = atomicAdd(&hist[hv[u]], 1);
      const int tr  = p * NK1 + hv[u];
      ents[p * BPART + pos] = ((tr & 63) << 16) | (b * NPARTS + p);
    }
  }
}

// ---------------- 64x128-tile bf16 MFMA GEMM (R3-proven core) ----------------
// 2-phase dbuf, BK=64, XOR-swizzled staging (swizzled global src + linear LDS
// dest [m104/m108], swizzled ds_read [rule #21]).
// MODE 0: out = relu(acc+bias) -> bf16 H  (+ z==1: transpose-cast W2)
// MODE 2: fused scatter: stage f32 tile (+bias+pe) to LDS, then stream the
//         precomputed consumer slice [glob64[by], glob64[by+1]) straight to out.
template <int K, int MODE, bool DO_W2T>
__global__ __launch_bounds__(256) void gemm_kernel(
    const unsigned short* __restrict__ A, const unsigned short* __restrict__ BT,
    const float* __restrict__ bias, const float* __restrict__ pe,
    unsigned short* __restrict__ outB, float* __restrict__ outF,
    const float* __restrict__ W2src, unsigned short* __restrict__ w2dst,
    const int* __restrict__ ents, const int* __restrict__ glob64) {
  __shared__ __align__(16) unsigned short smem[2 * 12288];   // 48 KB staging
  const int tid = threadIdx.x;

  if (DO_W2T && blockIdx.z == 1) {
    if (blockIdx.y >= 32) return;
    unsigned short (*ttile)[132] = (unsigned short (*)[132])smem;
    const int tk = blockIdx.y * 32, tn = blockIdx.x * 128;
#pragma unroll
    for (int q = 0; q < 4; ++q) {
      const int row = (tid >> 5) + q * 8, c4 = (tid & 31) * 4;
      const float4 v = *(const float4*)(W2src + (size_t)(tk + row) * ODIM + tn + c4);
      ttile[row][c4 + 0] = f2bf(v.x); ttile[row][c4 + 1] = f2bf(v.y);
      ttile[row][c4 + 2] = f2bf(v.z); ttile[row][c4 + 3] = f2bf(v.w);
    }
    __syncthreads();
#pragma unroll
    for (int q = 0; q < 4; ++q) {
      const int n = (tid >> 3) + q * 32, k4 = (tid & 7) * 4;
      ushort4 o;
      o.x = ttile[k4 + 0][n]; o.y = ttile[k4 + 1][n];
      o.z = ttile[k4 + 2][n]; o.w = ttile[k4 + 3][n];
      *(ushort4*)(w2dst + (size_t)(tn + n) * ODIM + tk + k4) = o;
    }
    return;
  }

  const int lane = tid & 63;
  const int wave = tid >> 6;
  const int wc   = wave * 32;
  const int brow = blockIdx.y * 64;
  const int bcol = blockIdx.x * 128;
  const int la   = lane & 15;
  const int hi   = lane >> 4;

  f32x4 acc[4][2];
#pragma unroll
  for (int m = 0; m < 4; ++m)
#pragma unroll
    for (int n = 0; n < 2; ++n)
#pragma unroll
      for (int r = 0; r < 4; ++r) acc[m][n][r] = 0.f;

  const int srow = tid >> 3;                       // 0..31
  const int skb  = (tid & 7) ^ (srow & 7);         // swizzled k-block
  const unsigned short* gA = A + (size_t)(brow + srow) * K + skb * 8;
  const unsigned short* gB = BT + (size_t)(bcol + srow) * K + skb * 8;

#define STAGE(b, kt)                                              \
  {                                                               \
    unsigned short* la_ = smem + (b) * 12288 + tid * 8;           \
    unsigned short* lb_ = la_ + 4096;                             \
    gload_lds16(gA + (kt), la_);                                  \
    gload_lds16(gA + (kt) + 32 * K, la_ + 2048);                  \
    gload_lds16(gB + (kt), lb_);                                  \
    gload_lds16(gB + (kt) + 32 * K, lb_ + 2048);                  \
    gload_lds16(gB + (kt) + 64 * K, lb_ + 4096);                  \
    gload_lds16(gB + (kt) + 96 * K, lb_ + 6144);                  \
  }

  STAGE(0, 0);
  asm volatile("s_waitcnt vmcnt(0)" ::: "memory");
  __builtin_amdgcn_s_barrier();

  const int NT = K / 64;
  for (int t = 0; t < NT; ++t) {
    const int cur = t & 1;
    if (t + 1 < NT) STAGE(cur ^ 1, (t + 1) * 64);

    const unsigned short* As = smem + cur * 12288;
    const unsigned short* Bs = As + 4096;
    s16x8 af[4][2], bf[2][2];
#pragma unroll
    for (int m = 0; m < 4; ++m)
#pragma unroll
      for (int ks = 0; ks < 2; ++ks)
        af[m][ks] = *(const s16x8*)(As + (m * 16 + la) * 64 +
                                    (((ks * 4 + hi) ^ (la & 7)) * 8));
#pragma unroll
    for (int n = 0; n < 2; ++n)
#pragma unroll
      for (int ks = 0; ks < 2; ++ks)
        bf[n][ks] = *(const s16x8*)(Bs + (wc + n * 16 + la) * 64 +
                                    (((ks * 4 + hi) ^ (la & 7)) * 8));
#pragma unroll
    for (int m = 0; m < 4; ++m)
#pragma unroll
      for (int n = 0; n < 2; ++n)
#pragma unroll
        for (int ks = 0; ks < 2; ++ks)
          acc[m][n] = __builtin_amdgcn_mfma_f32_16x16x32_bf16(af[m][ks], bf[n][ks],
                                                              acc[m][n], 0, 0, 0);
    asm volatile("s_waitcnt vmcnt(0)" ::: "memory");
    __builtin_amdgcn_sched_barrier(0);
    __builtin_amdgcn_s_barrier();
  }
#undef STAGE

  // epilogue: C/D layout col=lane&15, row=(lane>>4)*4+reg  [m89-verified]
  if constexpr (MODE == 0) {
#pragma unroll
    for (int m = 0; m < 4; ++m) {
      const int row0 = brow + m * 16 + hi * 4;
#pragma unroll
      for (int n = 0; n < 2; ++n) {
        const int col = bcol + wc + n * 16 + la;
        const float bv = bias[col];
#pragma unroll
        for (int r = 0; r < 4; ++r) {
          float v = acc[m][n][r] + bv;
          v = v > 0.f ? v : 0.f;
          outB[(size_t)(row0 + r) * ODIM + col] = f2bf(v);
        }
      }
    }
  } else {
    // ---- fused scatter: stage finished tile (+bias+pe) to LDS ----
    float (*tile)[128] = (float (*)[128])smem;   // 32 KB (reuses staging)
#pragma unroll
    for (int m = 0; m < 4; ++m) {
      const int trl = m * 16 + hi * 4;
#pragma unroll
      for (int n = 0; n < 2; ++n) {
        const int lcol = wc + n * 16 + la;
        const float bv = bias[bcol + lcol];
#pragma unroll
        for (int r = 0; r < 4; ++r) {
          const int tr = brow + trl + r;
          int p = tr / NK1; if (p > NPARTS - 1) p = NPARTS - 1;   // pad rows: never scattered
          tile[trl + r][lcol] = acc[m][n][r] + bv + pe[(size_t)p * ODIM + bcol + lcol];
        }
      }
    }
    __syncthreads();
    const int s0  = glob64[blockIdx.y];
    const int cnt = glob64[blockIdx.y + 1] - s0;
    const int hw  = wave * 2 + (lane >> 5);      // half-wave id 0..7
    const int l32 = lane & 31;
    for (int base = 0; base < cnt; base += 32) {
      int e[4];
#pragma unroll
      for (int j = 0; j < 4; ++j) {              // 4 independent loads issued together
        const int idx = base + hw + j * 8;
        e[j] = (idx < cnt) ? ents[s0 + idx] : -1;
      }
#pragma unroll
      for (int j = 0; j < 4; ++j) {
        if (e[j] >= 0) {
          const int local = (e[j] >> 16) & 63;
          const int orow  = e[j] & 0xFFFF;
          const f32x4 v = *(const f32x4*)&tile[local][l32 * 4];
          __builtin_nontemporal_store(
              v, (f32x4*)(outF + (size_t)orow * ODIM + bcol + l32 * 4));
        }
      }
    }
  }
}

// ---------------- launch ----------------
extern "C" void kernel_launch(void* const* d_in, const int* in_sizes, int n_in,
                              void* d_out, int out_size, void* d_ws, size_t ws_size,
                              hipStream_t stream) {
  const int*   hashes = (const int*)d_in[0];
  const float* emb    = (const float*)d_in[1];
  const float* W1     = (const float*)d_in[2];
  const float* b1     = (const float*)d_in[3];
  const float* W2     = (const float*)d_in[4];
  const float* b2     = (const float*)d_in[5];
  const float* pe     = (const float*)d_in[6];
  float* out = (float*)d_out;

  char* ws = (char*)d_ws;
  unsigned short* embB = (unsigned short*)(ws);                 // 4224*768*2  = 6,488,064
  unsigned short* w1t  = (unsigned short*)(ws + 6488064);       // 1024*768*2  = 1,572,864
  unsigned short* w2t  = (unsigned short*)(ws + 8060928);       // 1024*1024*2 = 2,097,152
  unsigned short* H    = (unsigned short*)(ws + 10158080);      // 4224*1024*2 = 8,650,752
  int*            ents = (int*)(ws + 18808832);                 // 65536*4 = 262,144
  int*            g64  = (int*)(ws + 19070976);                 // 67*4

  prep_kernel<<<EMB_BLOCKS + W1_BLOCKS + NPARTS, 256, 0, stream>>>(
      emb, W1, hashes, embB, w1t, ents, g64);

  // GEMM1 (z=0: 528 gemm blocks) + W2 transpose overlapped (z=1: 256 blocks)
  gemm_kernel<VAE, 0, true><<<dim3(8, 66, 2), 256, 0, stream>>>(
      embB, w1t, b1, nullptr, H, nullptr, W2, w2t, nullptr, nullptr);

  // GEMM2 fused with consumer scatter (output stream overlaps the grid's tail)
  gemm_kernel<ODIM, 2, false><<<dim3(8, 66, 1), 256, 0, stream>>>(
      H, w2t, b2, pe, nullptr, out, nullptr, nullptr, ents, g64);
}

// Round 12
// 93.739 us; speedup vs baseline: 1.0562x; 1.0562x over previous
//
#include <hip/hip_runtime.h>
#include <stdint.h>

// ---- problem constants ----
#define NPARTS 16
#define NK1    257            // rows per part (hash values 0..256)
#define ROWS   4112           // 257*16 distinct embedding rows
#define MPAD   4224           // 66*64, padded GEMM M
#define VAE    768
#define ODIM   1024
#define BROWS  65536          // 4096*16 output rows

typedef __attribute__((ext_vector_type(4))) float f32x4;
typedef __attribute__((ext_vector_type(8))) short s16x8;

static __device__ __forceinline__ unsigned short f2bf(float f) {
  union { float f; unsigned u; } v; v.f = f;
  unsigned x = v.u;
  unsigned r = x + 0x7FFFu + ((x >> 16) & 1u);   // RNE
  return (unsigned short)(r >> 16);
}

static __device__ __forceinline__ float bf2f(unsigned short s) {
  union { unsigned u; float f; } v; v.u = ((unsigned)s) << 16;
  return v.f;
}

static __device__ __forceinline__ void gload_lds16(const void* g, void* l) {
  __builtin_amdgcn_global_load_lds(
      (const __attribute__((address_space(1))) unsigned int*)g,
      (__attribute__((address_space(3))) unsigned int*)l, 16, 0, 0);
}

// ---------------- prep: cast emb -> bf16 (pad to MPAD rows); transpose-cast W1 ----
// (R3-proven) grid: [0,1024) emb cast; [1024,1792) W1 32x32 tiles
#define EMB_BLOCKS 1024
__global__ __launch_bounds__(256) void prep_kernel(
    const float* __restrict__ emb, const float* __restrict__ W1,
    unsigned short* __restrict__ embB, unsigned short* __restrict__ w1t) {
  __shared__ unsigned short tile[32][33];
  const int tid = threadIdx.x;
  const int bid = blockIdx.x;
  if (bid < EMB_BLOCKS) {
    const int NQ = MPAD * VAE / 4;   // 811008 quads
    for (int g = bid * 256 + tid; g < NQ; g += EMB_BLOCKS * 256) {
      const int i4 = g * 4;
      ushort4 o;
      if (i4 < ROWS * VAE) {
        const float4 v = *(const float4*)(emb + i4);
        o.x = f2bf(v.x); o.y = f2bf(v.y); o.z = f2bf(v.z); o.w = f2bf(v.w);
      } else {
        o.x = 0; o.y = 0; o.z = 0; o.w = 0;
      }
      *(ushort4*)(embB + i4) = o;
    }
  } else {
    const int tb = bid - EMB_BLOCKS;         // 768 tiles: 24 k-tiles x 32 n-tiles
    const int nkt = VAE / 32;
    const int tk = (tb % nkt) * 32;
    const int tn = (tb / nkt) * 32;
    const int r  = tid >> 3;                 // k-local
    const int c4 = (tid & 7) * 4;            // n-local
    const float4 v = *(const float4*)(W1 + (size_t)(tk + r) * ODIM + tn + c4);
    tile[r][c4 + 0] = f2bf(v.x);
    tile[r][c4 + 1] = f2bf(v.y);
    tile[r][c4 + 2] = f2bf(v.z);
    tile[r][c4 + 3] = f2bf(v.w);
    __syncthreads();
    ushort4 o;
    o.x = tile[c4 + 0][r];
    o.y = tile[c4 + 1][r];
    o.z = tile[c4 + 2][r];
    o.w = tile[c4 + 3][r];
    *(ushort4*)(w1t + (size_t)(tn + r) * VAE + tk + c4) = o;
  }
}

// ---------------- 64x128-tile bf16 MFMA GEMM ----------------
// R10 core + T4 counted-vmcnt reorder: STAGE(t+1) issued at loop top, then
// vmcnt(6) retires exactly stage-t's 6 loads (stage-t+1's stay in flight across
// the barrier and hide under the compute phase). 2 buffers, 48KB, 2 barriers/iter.
// XOR-swizzled staging [rule #21]: swizzled global src + linear LDS dest,
// swizzled ds_read -> conflict-free b128.
// MODE 0: out = relu(acc+bias)        -> bf16 H   (+ z==1: transpose-cast W2)
// MODE 2: out = acc+bias+pe[row/257]  -> bf16 T
template <int K, int MODE, bool DO_W2T>
__global__ __launch_bounds__(256) void gemm_kernel(
    const unsigned short* __restrict__ A, const unsigned short* __restrict__ BT,
    const float* __restrict__ bias, const float* __restrict__ pe,
    unsigned short* __restrict__ outB,
    const float* __restrict__ W2src, unsigned short* __restrict__ w2dst) {
  __shared__ __align__(16) unsigned short smem[2 * 12288];   // 48 KB staging
  const int tid = threadIdx.x;

  if (DO_W2T && blockIdx.z == 1) {
    if (blockIdx.y >= 32) return;
    unsigned short (*ttile)[132] = (unsigned short (*)[132])smem;
    const int tk = blockIdx.y * 32, tn = blockIdx.x * 128;
#pragma unroll
    for (int q = 0; q < 4; ++q) {
      const int row = (tid >> 5) + q * 8, c4 = (tid & 31) * 4;
      const float4 v = *(const float4*)(W2src + (size_t)(tk + row) * ODIM + tn + c4);
      ttile[row][c4 + 0] = f2bf(v.x); ttile[row][c4 + 1] = f2bf(v.y);
      ttile[row][c4 + 2] = f2bf(v.z); ttile[row][c4 + 3] = f2bf(v.w);
    }
    __syncthreads();
#pragma unroll
    for (int q = 0; q < 4; ++q) {
      const int n = (tid >> 3) + q * 32, k4 = (tid & 7) * 4;
      ushort4 o;
      o.x = ttile[k4 + 0][n]; o.y = ttile[k4 + 1][n];
      o.z = ttile[k4 + 2][n]; o.w = ttile[k4 + 3][n];
      *(ushort4*)(w2dst + (size_t)(tn + n) * ODIM + tk + k4) = o;
    }
    return;
  }

  const int lane = tid & 63;
  const int wave = tid >> 6;
  const int wc   = wave * 32;
  const int brow = blockIdx.y * 64;
  const int bcol = blockIdx.x * 128;
  const int la   = lane & 15;
  const int hi   = lane >> 4;

  f32x4 acc[4][2];
#pragma unroll
  for (int m = 0; m < 4; ++m)
#pragma unroll
    for (int n = 0; n < 2; ++n)
#pragma unroll
      for (int r = 0; r < 4; ++r) acc[m][n][r] = 0.f;

  const int srow = tid >> 3;                       // 0..31
  const int skb  = (tid & 7) ^ (srow & 7);         // swizzled k-block
  const unsigned short* gA = A + (size_t)(brow + srow) * K + skb * 8;
  const unsigned short* gB = BT + (size_t)(bcol + srow) * K + skb * 8;

#define STAGE(b, kt)                                              \
  {                                                               \
    unsigned short* la_ = smem + (b) * 12288 + tid * 8;           \
    unsigned short* lb_ = la_ + 4096;                             \
    gload_lds16(gA + (kt), la_);                                  \
    gload_lds16(gA + (kt) + 32 * K, la_ + 2048);                  \
    gload_lds16(gB + (kt), lb_);                                  \
    gload_lds16(gB + (kt) + 32 * K, lb_ + 2048);                  \
    gload_lds16(gB + (kt) + 64 * K, lb_ + 4096);                  \
    gload_lds16(gB + (kt) + 96 * K, lb_ + 6144);                  \
  }

  STAGE(0, 0);

  const int NT = K / 64;
  for (int t = 0; t < NT; ++t) {
    const int cur = t & 1;
    // issue next stage FIRST (writes buf cur^1, whose reads retired before the
    // previous iteration's end barrier)
    if (t + 1 < NT) {
      STAGE(cur ^ 1, (t + 1) * 64);
      // retire exactly stage-t's 6 loads; stage-t+1's 6 remain in flight
      asm volatile("s_waitcnt vmcnt(6)" ::: "memory");
    } else {
      asm volatile("s_waitcnt vmcnt(0)" ::: "memory");
    }
    __builtin_amdgcn_sched_barrier(0);
    __builtin_amdgcn_s_barrier();     // all waves: buf cur fully staged

    const unsigned short* As = smem + cur * 12288;
    const unsigned short* Bs = As + 4096;
    s16x8 af[4][2], bf[2][2];
#pragma unroll
    for (int m = 0; m < 4; ++m)
#pragma unroll
      for (int ks = 0; ks < 2; ++ks)
        af[m][ks] = *(const s16x8*)(As + (m * 16 + la) * 64 +
                                    (((ks * 4 + hi) ^ (la & 7)) * 8));
#pragma unroll
    for (int n = 0; n < 2; ++n)
#pragma unroll
      for (int ks = 0; ks < 2; ++ks)
        bf[n][ks] = *(const s16x8*)(Bs + (wc + n * 16 + la) * 64 +
                                    (((ks * 4 + hi) ^ (la & 7)) * 8));
    // pin fragment reads into regs before the end barrier (rule #18)
    asm volatile("s_waitcnt lgkmcnt(0)" ::: "memory");
    __builtin_amdgcn_sched_barrier(0);
#pragma unroll
    for (int m = 0; m < 4; ++m)
#pragma unroll
      for (int n = 0; n < 2; ++n)
#pragma unroll
        for (int ks = 0; ks < 2; ++ks)
          acc[m][n] = __builtin_amdgcn_mfma_f32_16x16x32_bf16(af[m][ks], bf[n][ks],
                                                              acc[m][n], 0, 0, 0);
    __builtin_amdgcn_s_barrier();     // reads of buf cur done -> next STAGE may overwrite
  }
#undef STAGE

  // epilogue: C/D layout col=lane&15, row=(lane>>4)*4+reg  [m89-verified]
#pragma unroll
  for (int m = 0; m < 4; ++m) {
    const int row0 = brow + m * 16 + hi * 4;
#pragma unroll
    for (int n = 0; n < 2; ++n) {
      const int col = bcol + wc + n * 16 + la;
      const float bv = bias[col];
      if (MODE == 0) {
#pragma unroll
        for (int r = 0; r < 4; ++r) {
          float v = acc[m][n][r] + bv;
          v = v > 0.f ? v : 0.f;
          outB[(size_t)(row0 + r) * ODIM + col] = f2bf(v);
        }
      } else {
#pragma unroll
        for (int r = 0; r < 4; ++r) {
          const int row = row0 + r;
          int p = row / NK1;
          if (p > NPARTS - 1) p = NPARTS - 1;   // padded rows: never gathered
          outB[(size_t)row * ODIM + col] =
              f2bf(acc[m][n][r] + bv + pe[(size_t)p * ODIM + col]);
        }
      }
    }
  }
}

// ---------------- gather: out[row] = f32(Tb[hash + (row&15)*257]) ----------------
// (R10-proven) XCD-affinity + fully lane-contiguous reads (512B/wave) and
// stores (1KB/wave).
__global__ __launch_bounds__(256) void gather_kernel(const int* __restrict__ hashes,
                                                     const unsigned short* __restrict__ Tb,
                                                     float* __restrict__ out) {
  const int xcd  = blockIdx.x & 7;
  const int bi   = blockIdx.x >> 3;            // 0..255
  const int wave = threadIdx.x >> 6;
  const int lane = threadIdx.x & 63;
  const int wl   = bi * 4 + wave;              // 0..1023
  const int p0   = xcd * 2;
#pragma unroll
  for (int i = 0; i < 8; ++i) {
    const int r     = wl + i * 1024;           // 0..8191
    const int batch = r >> 1;
    const int p     = p0 + (r & 1);
    const int orow  = batch * NPARTS + p;
    const int h = __builtin_amdgcn_readfirstlane(hashes[orow]);
    const unsigned short* srcrow = Tb + (size_t)(h + p * NK1) * ODIM;
    float* dstrow = out + (size_t)orow * ODIM;
#pragma unroll
    for (int q = 0; q < 4; ++q) {
      const int e0 = q * 256 + lane * 4;
      const ushort4 v = *(const ushort4*)(srcrow + e0);
      f32x4 f;
      f[0] = bf2f(v.x); f[1] = bf2f(v.y); f[2] = bf2f(v.z); f[3] = bf2f(v.w);
      __builtin_nontemporal_store(f, (f32x4*)(dstrow + e0));
    }
  }
}

// ---------------- launch ----------------
extern "C" void kernel_launch(void* const* d_in, const int* in_sizes, int n_in,
                              void* d_out, int out_size, void* d_ws, size_t ws_size,
                              hipStream_t stream) {
  const int*   hashes = (const int*)d_in[0];
  const float* emb    = (const float*)d_in[1];
  const float* W1     = (const float*)d_in[2];
  const float* b1     = (const float*)d_in[3];
  const float* W2     = (const float*)d_in[4];
  const float* b2     = (const float*)d_in[5];
  const float* pe     = (const float*)d_in[6];
  float* out = (float*)d_out;

  char* ws = (char*)d_ws;
  unsigned short* embB = (unsigned short*)(ws);                 // 4224*768*2  = 6,488,064
  unsigned short* w1t  = (unsigned short*)(ws + 6488064);       // 1024*768*2  = 1,572,864
  unsigned short* w2t  = (unsigned short*)(ws + 8060928);       // 1024*1024*2 = 2,097,152
  unsigned short* H    = (unsigned short*)(ws + 10158080);      // 4224*1024*2 = 8,650,752
  unsigned short* Tb   = (unsigned short*)(ws + 18808832);      // 4224*1024*2 = 8,650,752

  prep_kernel<<<EMB_BLOCKS + 768, 256, 0, stream>>>(emb, W1, embB, w1t);

  // GEMM1 (z=0: 528 gemm blocks) + W2 transpose overlapped (z=1: 256 blocks)
  gemm_kernel<VAE, 0, true><<<dim3(8, 66, 2), 256, 0, stream>>>(
      embB, w1t, b1, nullptr, H, W2, w2t);

  gemm_kernel<ODIM, 2, false><<<dim3(8, 66, 1), 256, 0, stream>>>(
      H, w2t, b2, pe, Tb, nullptr, nullptr);

  gather_kernel<<<2048, 256, 0, stream>>>(hashes, Tb, out);
}

// Round 13
// 91.790 us; speedup vs baseline: 1.0786x; 1.0212x over previous
//
#include <hip/hip_runtime.h>
#include <stdint.h>

// ---- problem constants ----
#define NPARTS 16
#define NK1    257            // rows per part (hash values 0..256)
#define ROWS   4112           // 257*16 distinct embedding rows
#define MPAD   4224           // 66*64, padded GEMM M
#define VAE    768
#define ODIM   1024
#define BROWS  65536          // 4096*16 output rows

typedef __attribute__((ext_vector_type(4))) float f32x4;
typedef __attribute__((ext_vector_type(8))) short s16x8;

static __device__ __forceinline__ unsigned short f2bf(float f) {
  union { float f; unsigned u; } v; v.f = f;
  unsigned x = v.u;
  unsigned r = x + 0x7FFFu + ((x >> 16) & 1u);   // RNE
  return (unsigned short)(r >> 16);
}

static __device__ __forceinline__ float bf2f(unsigned short s) {
  union { unsigned u; float f; } v; v.u = ((unsigned)s) << 16;
  return v.f;
}

static __device__ __forceinline__ void gload_lds16(const void* g, void* l) {
  __builtin_amdgcn_global_load_lds(
      (const __attribute__((address_space(1))) unsigned int*)g,
      (__attribute__((address_space(3))) unsigned int*)l, 16, 0, 0);
}

// ---------------- prep: cast emb -> bf16 (pad to MPAD rows); transpose-cast W1 ----
// (R3-proven) grid: [0,1024) emb cast; [1024,1792) W1 32x32 tiles
#define EMB_BLOCKS 1024
__global__ __launch_bounds__(256) void prep_kernel(
    const float* __restrict__ emb, const float* __restrict__ W1,
    unsigned short* __restrict__ embB, unsigned short* __restrict__ w1t) {
  __shared__ unsigned short tile[32][33];
  const int tid = threadIdx.x;
  const int bid = blockIdx.x;
  if (bid < EMB_BLOCKS) {
    const int NQ = MPAD * VAE / 4;   // 811008 quads
    for (int g = bid * 256 + tid; g < NQ; g += EMB_BLOCKS * 256) {
      const int i4 = g * 4;
      ushort4 o;
      if (i4 < ROWS * VAE) {
        const float4 v = *(const float4*)(emb + i4);
        o.x = f2bf(v.x); o.y = f2bf(v.y); o.z = f2bf(v.z); o.w = f2bf(v.w);
      } else {
        o.x = 0; o.y = 0; o.z = 0; o.w = 0;
      }
      *(ushort4*)(embB + i4) = o;
    }
  } else {
    const int tb = bid - EMB_BLOCKS;         // 768 tiles: 24 k-tiles x 32 n-tiles
    const int nkt = VAE / 32;
    const int tk = (tb % nkt) * 32;
    const int tn = (tb / nkt) * 32;
    const int r  = tid >> 3;                 // k-local
    const int c4 = (tid & 7) * 4;            // n-local
    const float4 v = *(const float4*)(W1 + (size_t)(tk + r) * ODIM + tn + c4);
    tile[r][c4 + 0] = f2bf(v.x);
    tile[r][c4 + 1] = f2bf(v.y);
    tile[r][c4 + 2] = f2bf(v.z);
    tile[r][c4 + 3] = f2bf(v.w);
    __syncthreads();
    ushort4 o;
    o.x = tile[c4 + 0][r];
    o.y = tile[c4 + 1][r];
    o.z = tile[c4 + 2][r];
    o.w = tile[c4 + 3][r];
    *(ushort4*)(w1t + (size_t)(tn + r) * VAE + tk + c4) = o;
  }
}

// ---------------- 64x128-tile bf16 MFMA GEMM (R3/R10-proven core, unchanged) --
// 2-phase dbuf, BK=64, XOR-swizzled staging (swizzled global src + linear LDS
// dest [m104/m108], swizzled ds_read [rule #21]).
// MODE 0: out = relu(acc+bias)        -> bf16 H   (+ z==1: transpose-cast W2)
// MODE 2: out = acc+bias+pe[row/257]  -> bf16 T
template <int K, int MODE, bool DO_W2T>
__global__ __launch_bounds__(256) void gemm_kernel(
    const unsigned short* __restrict__ A, const unsigned short* __restrict__ BT,
    const float* __restrict__ bias, const float* __restrict__ pe,
    unsigned short* __restrict__ outB,
    const float* __restrict__ W2src, unsigned short* __restrict__ w2dst) {
  __shared__ __align__(16) unsigned short smem[2 * 12288];   // 48 KB staging
  const int tid = threadIdx.x;

  if (DO_W2T && blockIdx.z == 1) {
    if (blockIdx.y >= 32) return;
    unsigned short (*ttile)[132] = (unsigned short (*)[132])smem;
    const int tk = blockIdx.y * 32, tn = blockIdx.x * 128;
#pragma unroll
    for (int q = 0; q < 4; ++q) {
      const int row = (tid >> 5) + q * 8, c4 = (tid & 31) * 4;
      const float4 v = *(const float4*)(W2src + (size_t)(tk + row) * ODIM + tn + c4);
      ttile[row][c4 + 0] = f2bf(v.x); ttile[row][c4 + 1] = f2bf(v.y);
      ttile[row][c4 + 2] = f2bf(v.z); ttile[row][c4 + 3] = f2bf(v.w);
    }
    __syncthreads();
#pragma unroll
    for (int q = 0; q < 4; ++q) {
      const int n = (tid >> 3) + q * 32, k4 = (tid & 7) * 4;
      ushort4 o;
      o.x = ttile[k4 + 0][n]; o.y = ttile[k4 + 1][n];
      o.z = ttile[k4 + 2][n]; o.w = ttile[k4 + 3][n];
      *(ushort4*)(w2dst + (size_t)(tn + n) * ODIM + tk + k4) = o;
    }
    return;
  }

  const int lane = tid & 63;
  const int wave = tid >> 6;
  const int wc   = wave * 32;
  const int brow = blockIdx.y * 64;
  const int bcol = blockIdx.x * 128;
  const int la   = lane & 15;
  const int hi   = lane >> 4;

  f32x4 acc[4][2];
#pragma unroll
  for (int m = 0; m < 4; ++m)
#pragma unroll
    for (int n = 0; n < 2; ++n)
#pragma unroll
      for (int r = 0; r < 4; ++r) acc[m][n][r] = 0.f;

  const int srow = tid >> 3;                       // 0..31
  const int skb  = (tid & 7) ^ (srow & 7);         // swizzled k-block
  const unsigned short* gA = A + (size_t)(brow + srow) * K + skb * 8;
  const unsigned short* gB = BT + (size_t)(bcol + srow) * K + skb * 8;

#define STAGE(b, kt)                                              \
  {                                                               \
    unsigned short* la_ = smem + (b) * 12288 + tid * 8;           \
    unsigned short* lb_ = la_ + 4096;                             \
    gload_lds16(gA + (kt), la_);                                  \
    gload_lds16(gA + (kt) + 32 * K, la_ + 2048);                  \
    gload_lds16(gB + (kt), lb_);                                  \
    gload_lds16(gB + (kt) + 32 * K, lb_ + 2048);                  \
    gload_lds16(gB + (kt) + 64 * K, lb_ + 4096);                  \
    gload_lds16(gB + (kt) + 96 * K, lb_ + 6144);                  \
  }

  STAGE(0, 0);
  asm volatile("s_waitcnt vmcnt(0)" ::: "memory");
  __builtin_amdgcn_s_barrier();

  const int NT = K / 64;
  for (int t = 0; t < NT; ++t) {
    const int cur = t & 1;
    if (t + 1 < NT) STAGE(cur ^ 1, (t + 1) * 64);

    const unsigned short* As = smem + cur * 12288;
    const unsigned short* Bs = As + 4096;
    s16x8 af[4][2], bf[2][2];
#pragma unroll
    for (int m = 0; m < 4; ++m)
#pragma unroll
      for (int ks = 0; ks < 2; ++ks)
        af[m][ks] = *(const s16x8*)(As + (m * 16 + la) * 64 +
                                    (((ks * 4 + hi) ^ (la & 7)) * 8));
#pragma unroll
    for (int n = 0; n < 2; ++n)
#pragma unroll
      for (int ks = 0; ks < 2; ++ks)
        bf[n][ks] = *(const s16x8*)(Bs + (wc + n * 16 + la) * 64 +
                                    (((ks * 4 + hi) ^ (la & 7)) * 8));
#pragma unroll
    for (int m = 0; m < 4; ++m)
#pragma unroll
      for (int n = 0; n < 2; ++n)
#pragma unroll
        for (int ks = 0; ks < 2; ++ks)
          acc[m][n] = __builtin_amdgcn_mfma_f32_16x16x32_bf16(af[m][ks], bf[n][ks],
                                                              acc[m][n], 0, 0, 0);
    asm volatile("s_waitcnt vmcnt(0)" ::: "memory");
    __builtin_amdgcn_sched_barrier(0);
    __builtin_amdgcn_s_barrier();
  }
#undef STAGE

  // epilogue: C/D layout col=lane&15, row=(lane>>4)*4+reg  [m89-verified]
#pragma unroll
  for (int m = 0; m < 4; ++m) {
    const int row0 = brow + m * 16 + hi * 4;
#pragma unroll
    for (int n = 0; n < 2; ++n) {
      const int col = bcol + wc + n * 16 + la;
      const float bv = bias[col];
      if (MODE == 0) {
#pragma unroll
        for (int r = 0; r < 4; ++r) {
          float v = acc[m][n][r] + bv;
          v = v > 0.f ? v : 0.f;
          outB[(size_t)(row0 + r) * ODIM + col] = f2bf(v);
        }
      } else {
#pragma unroll
        for (int r = 0; r < 4; ++r) {
          const int row = row0 + r;
          int p = row / NK1;
          if (p > NPARTS - 1) p = NPARTS - 1;   // padded rows: never gathered
          outB[(size_t)row * ODIM + col] =
              f2bf(acc[m][n][r] + bv + pe[(size_t)p * ODIM + col]);
        }
      }
    }
  }
}

// ---------------- gather: out[row] = f32(Tb[hash + (row&15)*257]) ----------------
// (R10-proven layout) XCD-affinity + fully lane-contiguous reads (512B/wave) and
// stores (1KB/wave). New vs R10: all 8 hash values prefetched upfront
// (independent loads -> single latency exposure instead of 8 serial rounds).
__global__ __launch_bounds__(256) void gather_kernel(const int* __restrict__ hashes,
                                                     const unsigned short* __restrict__ Tb,
                                                     float* __restrict__ out) {
  const int xcd  = blockIdx.x & 7;
  const int bi   = blockIdx.x >> 3;            // 0..255
  const int wave = threadIdx.x >> 6;
  const int lane = threadIdx.x & 63;
  const int wl   = bi * 4 + wave;              // 0..1023
  const int p0   = xcd * 2;

  int hv[8], orow[8];
#pragma unroll
  for (int i = 0; i < 8; ++i) {                // independent hash loads, issued together
    const int r     = wl + i * 1024;           // 0..8191
    const int p     = p0 + (r & 1);
    orow[i] = (r >> 1) * NPARTS + p;
    hv[i]   = hashes[orow[i]];
  }
#pragma unroll
  for (int i = 0; i < 8; ++i) {
    const int r = wl + i * 1024;
    const int p = p0 + (r & 1);
    const int h = __builtin_amdgcn_readfirstlane(hv[i]);
    const unsigned short* srcrow = Tb + (size_t)(h + p * NK1) * ODIM;
    float* dstrow = out + (size_t)orow[i] * ODIM;
#pragma unroll
    for (int q = 0; q < 4; ++q) {
      const int e0 = q * 256 + lane * 4;
      const ushort4 v = *(const ushort4*)(srcrow + e0);
      f32x4 f;
      f[0] = bf2f(v.x); f[1] = bf2f(v.y); f[2] = bf2f(v.z); f[3] = bf2f(v.w);
      __builtin_nontemporal_store(f, (f32x4*)(dstrow + e0));
    }
  }
}

// ---------------- launch ----------------
extern "C" void kernel_launch(void* const* d_in, const int* in_sizes, int n_in,
                              void* d_out, int out_size, void* d_ws, size_t ws_size,
                              hipStream_t stream) {
  const int*   hashes = (const int*)d_in[0];
  const float* emb    = (const float*)d_in[1];
  const float* W1     = (const float*)d_in[2];
  const float* b1     = (const float*)d_in[3];
  const float* W2     = (const float*)d_in[4];
  const float* b2     = (const float*)d_in[5];
  const float* pe     = (const float*)d_in[6];
  float* out = (float*)d_out;

  char* ws = (char*)d_ws;
  unsigned short* embB = (unsigned short*)(ws);                 // 4224*768*2  = 6,488,064
  unsigned short* w1t  = (unsigned short*)(ws + 6488064);       // 1024*768*2  = 1,572,864
  unsigned short* w2t  = (unsigned short*)(ws + 8060928);       // 1024*1024*2 = 2,097,152
  unsigned short* H    = (unsigned short*)(ws + 10158080);      // 4224*1024*2 = 8,650,752
  unsigned short* Tb   = (unsigned short*)(ws + 18808832);      // 4224*1024*2 = 8,650,752

  prep_kernel<<<EMB_BLOCKS + 768, 256, 0, stream>>>(emb, W1, embB, w1t);

  // GEMM1 (z=0: 528 gemm blocks) + W2 transpose overlapped (z=1: 256 blocks)
  gemm_kernel<VAE, 0, true><<<dim3(8, 66, 2), 256, 0, stream>>>(
      embB, w1t, b1, nullptr, H, W2, w2t);

  gemm_kernel<ODIM, 2, false><<<dim3(8, 66, 1), 256, 0, stream>>>(
      H, w2t, b2, pe, Tb, nullptr, nullptr);

  gather_kernel<<<2048, 256, 0, stream>>>(hashes, Tb, out);
}